// Round 1
// baseline (735.695 us; speedup 1.0000x reference)
//
#include <hip/hip_runtime.h>

#define SHFL16(v, k) __shfl((v), (k), 16)

__global__ __launch_bounds__(256) void ekf_kernel(
    const float* __restrict__ g_state, const float* __restrict__ g_obs,
    const float* __restrict__ g_u,     const float* __restrict__ g_P,
    const float* __restrict__ g_A,     const float* __restrict__ g_B,
    const float* __restrict__ g_C,     const float* __restrict__ g_D,
    const float* __restrict__ g_c1,    const float* __restrict__ g_c2,
    const float* __restrict__ g_Q,     const float* __restrict__ g_R,
    float* __restrict__ o_xp, float* __restrict__ o_Pn, int bn)
{
    const int tid  = blockIdx.x * blockDim.x + threadIdx.x;
    const int item = tid >> 4;            // 16 lanes per batch item
    if (item >= bn) return;               // grid exact; group-uniform anyway
    const int r    = tid & 15;            // row index this lane owns
    const int rc   = r < 15 ? r : 14;     // clamped row for loads (lane 15 idle)
    const int rc6  = r < 6 ? r : 5;

    // ---- loads: lane r holds row r of each matrix ----
    float a[15], p[15], c[15];
    const float* Ab = g_A + (size_t)item * 225 + rc * 15;
    const float* Pb = g_P + (size_t)item * 225 + rc * 15;
    const float* Cb = g_C + (size_t)item * 90  + rc6 * 15;
    #pragma unroll
    for (int j = 0; j < 15; ++j) { a[j] = Ab[j]; p[j] = Pb[j]; c[j] = Cb[j]; }
    float b[6], dd[6], q[6], rr[6];
    const float* Bb = g_B + (size_t)item * 90 + rc * 6;
    const float* Db = g_D + (size_t)item * 36 + rc6 * 6;
    const float* Qb = g_Q + (size_t)item * 36 + rc6 * 6;
    const float* Rb = g_R + (size_t)item * 36 + rc6 * 6;
    #pragma unroll
    for (int j = 0; j < 6; ++j) { b[j] = Bb[j]; dd[j] = Db[j]; q[j] = Qb[j]; rr[j] = Rb[j]; }
    float x    = g_state[(size_t)item * 15 + rc];
    float uu   = g_u[(size_t)item * 6 + rc6];
    float c1v  = g_c1[(size_t)item * 15 + rc];
    float obsv = g_obs[(size_t)item * 6 + rc6];
    float c2v  = g_c2[(size_t)item * 6 + rc6];

    // ---- xp = A x + B u + c1 ----
    float xp = c1v;
    #pragma unroll
    for (int j = 0; j < 15; ++j) xp += a[j] * SHFL16(x, j);
    #pragma unroll
    for (int j = 0; j < 6; ++j)  xp += b[j] * SHFL16(uu, j);

    // ---- T1 = A * P ----
    float t1[15];
    #pragma unroll
    for (int j = 0; j < 15; ++j) t1[j] = 0.f;
    #pragma unroll
    for (int k = 0; k < 15; ++k) {
        float ak = a[k];
        #pragma unroll
        for (int j = 0; j < 15; ++j) t1[j] += ak * SHFL16(p[j], k);
    }
    // ---- Pp = T1 * A^T ----
    float pp[15];
    #pragma unroll
    for (int j = 0; j < 15; ++j) {
        float s = 0.f;
        #pragma unroll
        for (int k = 0; k < 15; ++k) s += t1[k] * SHFL16(a[k], j);
        pp[j] = s;
    }
    // ---- T2 = B * Q ----
    float t2[6];
    #pragma unroll
    for (int j = 0; j < 6; ++j) t2[j] = 0.f;
    #pragma unroll
    for (int k = 0; k < 6; ++k) {
        float bk = b[k];
        #pragma unroll
        for (int j = 0; j < 6; ++j) t2[j] += bk * SHFL16(q[j], k);
    }
    // ---- Pp += T2 * B^T ----
    #pragma unroll
    for (int j = 0; j < 15; ++j) {
        float s = 0.f;
        #pragma unroll
        for (int k = 0; k < 6; ++k) s += t2[k] * SHFL16(b[k], j);
        pp[j] += s;
    }

    // ---- PpCt = Pp * C^T  (15x6) ----
    float ppct[6];
    #pragma unroll
    for (int j = 0; j < 6; ++j) {
        float s = 0.f;
        #pragma unroll
        for (int k = 0; k < 15; ++k) s += pp[k] * SHFL16(c[k], j);
        ppct[j] = s;
    }
    // ---- S = C * PpCt + R  (6x6, rows r<6); augment [S | I] ----
    float sm[12];
    #pragma unroll
    for (int j = 0; j < 6; ++j) {
        float s = rr[j];
        #pragma unroll
        for (int k = 0; k < 15; ++k) s += c[k] * SHFL16(ppct[j], k);
        sm[j] = s;
        sm[6 + j] = (r == j) ? 1.f : 0.f;
    }
    // ---- Gauss-Jordan invert S (SPD -> no pivoting needed) ----
    #pragma unroll
    for (int k = 0; k < 6; ++k) {
        float piv = SHFL16(sm[k], k);
        float ip  = 1.f / piv;
        float f   = sm[k];
        #pragma unroll
        for (int j = 0; j < 12; ++j) {
            float prj = SHFL16(sm[j], k) * ip;   // normalized pivot-row elem
            sm[j] = (r == k) ? prj : (sm[j] - f * prj);
        }
    }
    // ---- K = PpCt * Sinv  (15x6) ----
    float kk[6];
    #pragma unroll
    for (int j = 0; j < 6; ++j) kk[j] = 0.f;
    #pragma unroll
    for (int k = 0; k < 6; ++k) {
        float pk = ppct[k];
        #pragma unroll
        for (int j = 0; j < 6; ++j) kk[j] += pk * SHFL16(sm[6 + j], k);
    }
    // ---- e = obs - (C x + D u + c2)  (rows r<6) ----
    float ev = obsv - c2v;
    #pragma unroll
    for (int k = 0; k < 15; ++k) ev -= c[k] * SHFL16(x, k);
    #pragma unroll
    for (int k = 0; k < 6; ++k)  ev -= dd[k] * SHFL16(uu, k);
    // ---- xp += K e ----
    #pragma unroll
    for (int j = 0; j < 6; ++j) xp += kk[j] * SHFL16(ev, j);

    // ---- IKC = I - K*C  (15x15) ----
    float ikc[15];
    #pragma unroll
    for (int j = 0; j < 15; ++j) ikc[j] = (r == j) ? 1.f : 0.f;
    #pragma unroll
    for (int k = 0; k < 6; ++k) {
        float kkk = kk[k];
        #pragma unroll
        for (int j = 0; j < 15; ++j) ikc[j] -= kkk * SHFL16(c[j], k);
    }
    // ---- T3 = IKC * Pp ----
    float t3[15];
    #pragma unroll
    for (int j = 0; j < 15; ++j) t3[j] = 0.f;
    #pragma unroll
    for (int k = 0; k < 15; ++k) {
        float ik = ikc[k];
        #pragma unroll
        for (int j = 0; j < 15; ++j) t3[j] += ik * SHFL16(pp[j], k);
    }
    // ---- Pn = T3 * IKC^T ----
    float pn[15];
    #pragma unroll
    for (int j = 0; j < 15; ++j) {
        float s = 0.f;
        #pragma unroll
        for (int k = 0; k < 15; ++k) s += t3[k] * SHFL16(ikc[k], j);
        pn[j] = s;
    }
    // ---- KR = K * R ----
    float kr[6];
    #pragma unroll
    for (int j = 0; j < 6; ++j) kr[j] = 0.f;
    #pragma unroll
    for (int k = 0; k < 6; ++k) {
        float kkk = kk[k];
        #pragma unroll
        for (int j = 0; j < 6; ++j) kr[j] += kkk * SHFL16(rr[j], k);
    }
    // ---- Pn += KR * K^T ----
    #pragma unroll
    for (int j = 0; j < 15; ++j) {
        float s = 0.f;
        #pragma unroll
        for (int k = 0; k < 6; ++k) s += kr[k] * SHFL16(kk[k], j);
        pn[j] += s;
    }

    // ---- store ----
    if (r < 15) {
        o_xp[(size_t)item * 15 + r] = xp;
        float* prow = o_Pn + (size_t)item * 225 + r * 15;
        #pragma unroll
        for (int j = 0; j < 15; ++j) prow[j] = pn[j];
    }
}

extern "C" void kernel_launch(void* const* d_in, const int* in_sizes, int n_in,
                              void* d_out, int out_size, void* d_ws, size_t ws_size,
                              hipStream_t stream) {
    const float* g_state = (const float*)d_in[0];
    const float* g_obs   = (const float*)d_in[1];
    const float* g_u     = (const float*)d_in[2];
    const float* g_P     = (const float*)d_in[3];
    const float* g_A     = (const float*)d_in[4];
    const float* g_B     = (const float*)d_in[5];
    const float* g_C     = (const float*)d_in[6];
    const float* g_D     = (const float*)d_in[7];
    const float* g_c1    = (const float*)d_in[8];
    const float* g_c2    = (const float*)d_in[9];
    const float* g_Q     = (const float*)d_in[10];
    const float* g_R     = (const float*)d_in[11];

    const int bn = in_sizes[0] / 15;
    float* o_xp = (float*)d_out;
    float* o_pn = o_xp + (size_t)bn * 15;

    const int threads = 256;
    const int blocks  = (bn * 16 + threads - 1) / threads;
    ekf_kernel<<<blocks, threads, 0, stream>>>(
        g_state, g_obs, g_u, g_P, g_A, g_B, g_C, g_D, g_c1, g_c2, g_Q, g_R,
        o_xp, o_pn, bn);
}